// Round 3
// baseline (2332.215 us; speedup 1.0000x reference)
//
#include <hip/hip_runtime.h>
#include <hip/hip_bf16.h>

#define USER_N   100000
#define ITEM_N   200000
#define N_NODES  300000           // USER_N + ITEM_N
#define LATDIM   64
#define N_EDGES  9600000
#define N_LAYERS 3

// bucketed counting sort: bucket = row >> 6  (64 rows per bucket)
#define B_SHIFT  6
#define B_ROWS   64
#define NB       ((N_NODES + B_ROWS - 1) / B_ROWS)    // 4688
#define SEG      ((NB + 1023) / 1024)                 // 5

// ---------------------------------------------------------------------------
// copy concat(u, i) -> cur (ws) and acc (d_out), float4-vectorized
// ---------------------------------------------------------------------------
__global__ void copy_concat_kernel(const float* __restrict__ u,
                                   const float* __restrict__ it,
                                   float* __restrict__ cur,
                                   float* __restrict__ acc,
                                   int n4u, int n4total) {
    int stride = gridDim.x * blockDim.x;
    for (int i = blockIdx.x * blockDim.x + threadIdx.x; i < n4total; i += stride) {
        float4 v = (i < n4u) ? ((const float4*)u)[i]
                             : ((const float4*)it)[i - n4u];
        ((float4*)cur)[i] = v;
        ((float4*)acc)[i] = v;
    }
}

// ---------------------------------------------------------------------------
// step 1: per-bucket histogram (4688 counters, ~2048 hits each)
// ---------------------------------------------------------------------------
__global__ void bucket_hist_kernel(const int* __restrict__ row,
                                   int* __restrict__ gcnt) {
    int stride = gridDim.x * blockDim.x;
    for (int e = blockIdx.x * blockDim.x + threadIdx.x; e < N_EDGES; e += stride)
        atomicAdd(&gcnt[row[e] >> B_SHIFT], 1);
}

// ---------------------------------------------------------------------------
// step 2: exclusive scan of NB bucket counts (single block, 1024 threads)
// writes bucketStart[0..NB], bucketCur (=starts), rowPtr[N_NODES]=N_EDGES
// ---------------------------------------------------------------------------
__global__ void scan_buckets_kernel(const int* __restrict__ gcnt,
                                    int* __restrict__ bstart,
                                    int* __restrict__ bcur,
                                    int* __restrict__ rowPtr) {
    __shared__ int lds[1024];
    int t = threadIdx.x;
    int base = t * SEG;
    int loc[SEG];
    int s = 0;
    #pragma unroll
    for (int k = 0; k < SEG; ++k) {
        int i = base + k;
        int v = (i < NB) ? gcnt[i] : 0;
        loc[k] = v;
        s += v;
    }
    lds[t] = s;
    __syncthreads();
    for (int off = 1; off < 1024; off <<= 1) {
        int add = (t >= off) ? lds[t - off] : 0;
        __syncthreads();
        lds[t] += add;
        __syncthreads();
    }
    int ex = lds[t] - s;              // exclusive prefix of this segment
    #pragma unroll
    for (int k = 0; k < SEG; ++k) {
        int i = base + k;
        if (i < NB) { bstart[i] = ex; bcur[i] = ex; }
        ex += loc[k];
    }
    if (t == 1023) {
        bstart[NB] = lds[1023];       // = N_EDGES
        rowPtr[N_NODES] = N_EDGES;
    }
}

// ---------------------------------------------------------------------------
// step 3 (phase A): partition edges into bucket-contiguous regions of temp.
// Write frontier = NB cache lines (~300 KB) -> L2-resident, no amplification.
// entry: key = row_local(6b)<<19 | col(19b), val bits
// ---------------------------------------------------------------------------
__global__ void partition_kernel(const int*   __restrict__ row,
                                 const int*   __restrict__ col,
                                 const float* __restrict__ val,
                                 int*         __restrict__ bcur,
                                 int2*        __restrict__ temp) {
    int stride = gridDim.x * blockDim.x;
    for (int e = blockIdx.x * blockDim.x + threadIdx.x; e < N_EDGES; e += stride) {
        int r = row[e];
        int b = r >> B_SHIFT;
        int pos = atomicAdd(&bcur[b], 1);
        temp[pos] = make_int2(((r & (B_ROWS - 1)) << 19) | col[e],
                              __float_as_int(val[e]));
    }
}

// ---------------------------------------------------------------------------
// step 4 (phase B): per-bucket row sort. One block per bucket (~2048 entries).
// LDS hist(64) + wave shfl-scan -> also emits global rowPtr slice.
// Scatter into 16 KB L2-resident region of final colval.
// ---------------------------------------------------------------------------
__global__ void bucket_sort_kernel(const int*  __restrict__ bstart,
                                   const int2* __restrict__ temp,
                                   int2*       __restrict__ colval,
                                   int*        __restrict__ rowPtr) {
    __shared__ int hist[B_ROWS];
    __shared__ int curs[B_ROWS];
    int b   = blockIdx.x;
    int tid = threadIdx.x;
    int beg = bstart[b];
    int end = bstart[b + 1];

    if (tid < B_ROWS) hist[tid] = 0;
    __syncthreads();
    for (int i = beg + tid; i < end; i += 256)
        atomicAdd(&hist[((unsigned)temp[i].x) >> 19], 1);
    __syncthreads();

    if (tid < B_ROWS) {               // first wave: shfl inclusive scan
        int v = hist[tid];
        int inc = v;
        #pragma unroll
        for (int d = 1; d < B_ROWS; d <<= 1) {
            int o = __shfl_up(inc, d, 64);
            if (tid >= d) inc += o;
        }
        int ex = inc - v;
        curs[tid] = ex;
        int r = (b << B_SHIFT) + tid;
        if (r < N_NODES) rowPtr[r] = beg + ex;
    }
    __syncthreads();

    for (int i = beg + tid; i < end; i += 256) {
        int2 kv = temp[i];
        int rl = ((unsigned)kv.x) >> 19;
        int c  = kv.x & 0x7FFFF;
        int p  = beg + atomicAdd(&curs[rl], 1);
        colval[p] = make_int2(c, kv.y);
    }
}

// ---------------------------------------------------------------------------
// CSR SpMM, atomic-free: 16 lanes per row, lane q owns dims [4q, 4q+4).
// y[r] = sum_e val*x[col];  acc[r] += y[r] fused.  storeY=0 skips y write.
// ---------------------------------------------------------------------------
__global__ void spmm_csr_kernel(const int*  __restrict__ rp,
                                const int2* __restrict__ cv,
                                const float* __restrict__ x,
                                float*       __restrict__ y,
                                float*       __restrict__ acc,
                                int storeY) {
    int g = (blockIdx.x * blockDim.x + threadIdx.x) >> 4;   // row
    if (g >= N_NODES) return;
    int q = threadIdx.x & 15;
    int beg = rp[g];
    int end = rp[g + 1];
    const float4* x4 = (const float4*)x;

    float4 s = make_float4(0.f, 0.f, 0.f, 0.f);
    int i = beg;
    for (; i + 4 <= end; i += 4) {                 // 4 gathers in flight
        int2 c0 = cv[i], c1 = cv[i + 1], c2 = cv[i + 2], c3 = cv[i + 3];
        float4 g0 = x4[(size_t)c0.x * 16 + q];
        float4 g1 = x4[(size_t)c1.x * 16 + q];
        float4 g2 = x4[(size_t)c2.x * 16 + q];
        float4 g3 = x4[(size_t)c3.x * 16 + q];
        float v0 = __int_as_float(c0.y), v1 = __int_as_float(c1.y);
        float v2 = __int_as_float(c2.y), v3 = __int_as_float(c3.y);
        s.x += g0.x * v0; s.y += g0.y * v0; s.z += g0.z * v0; s.w += g0.w * v0;
        s.x += g1.x * v1; s.y += g1.y * v1; s.z += g1.z * v1; s.w += g1.w * v1;
        s.x += g2.x * v2; s.y += g2.y * v2; s.z += g2.z * v2; s.w += g2.w * v2;
        s.x += g3.x * v3; s.y += g3.y * v3; s.z += g3.z * v3; s.w += g3.w * v3;
    }
    for (; i < end; ++i) {
        int2 cc = cv[i];
        float4 gg = x4[(size_t)cc.x * 16 + q];
        float v  = __int_as_float(cc.y);
        s.x += gg.x * v; s.y += gg.y * v; s.z += gg.z * v; s.w += gg.w * v;
    }

    size_t o = (size_t)g * 16 + q;
    float4 a = ((const float4*)acc)[o];
    a.x += s.x; a.y += s.y; a.z += s.z; a.w += s.w;
    ((float4*)acc)[o] = a;
    if (storeY) ((float4*)y)[o] = s;
}

// ---------------------------------------------------------------------------
// Fallback path (R0): COO atomic SpMM + acc add
// ---------------------------------------------------------------------------
__global__ void spmm_atomic_kernel(const int*   __restrict__ row,
                                   const int*   __restrict__ col,
                                   const float* __restrict__ val,
                                   const float* __restrict__ x,
                                   float*       __restrict__ y) {
    const int total = N_EDGES * 16;
    int stride = gridDim.x * blockDim.x;
    for (int t = blockIdx.x * blockDim.x + threadIdx.x; t < total; t += stride) {
        int e = t >> 4;
        int q = t & 15;
        int r = row[e];
        int c = col[e];
        float v = val[e];
        float4 g = ((const float4*)x)[c * 16 + q];
        float* yp = y + r * 64 + q * 4;
        atomicAdd(yp + 0, g.x * v);
        atomicAdd(yp + 1, g.y * v);
        atomicAdd(yp + 2, g.z * v);
        atomicAdd(yp + 3, g.w * v);
    }
}

__global__ void acc_add_kernel(float* __restrict__ acc,
                               const float* __restrict__ add,
                               int n4) {
    int stride = gridDim.x * blockDim.x;
    for (int i = blockIdx.x * blockDim.x + threadIdx.x; i < n4; i += stride) {
        float4 a = ((const float4*)acc)[i];
        float4 b = ((const float4*)add)[i];
        a.x += b.x; a.y += b.y; a.z += b.z; a.w += b.w;
        ((float4*)acc)[i] = a;
    }
}

extern "C" void kernel_launch(void* const* d_in, const int* in_sizes, int n_in,
                              void* d_out, int out_size, void* d_ws, size_t ws_size,
                              hipStream_t stream) {
    const float* uEmb = (const float*)d_in[0];
    const float* iEmb = (const float*)d_in[1];
    const int*   row  = (const int*)  d_in[2];
    const int*   col  = (const int*)  d_in[3];
    const float* val  = (const float*)d_in[4];

    float* acc = (float*)d_out;

    const int n4total = N_NODES * (LATDIM / 4);
    const int n4u     = USER_N  * (LATDIM / 4);
    const size_t embBytes = (size_t)N_NODES * LATDIM * sizeof(float);

    const int BLK = 256;
    const int GRID_MEM = 2048;

    // ---- workspace layout ----
    auto align256 = [](size_t x) { return (x + 255) & ~(size_t)255; };
    size_t off = 0;
    size_t o_cur     = off; off += align256(embBytes);
    size_t o_nxt     = off; off += align256(embBytes);      // phase-A temp shares this
    size_t o_colval  = off; off += align256((size_t)N_EDGES * 8);
    size_t o_rowptr  = off; off += align256(((size_t)N_NODES + 1) * 4);
    size_t o_gcnt    = off; off += align256((size_t)NB * 4);
    size_t o_bstart  = off; off += align256(((size_t)NB + 1) * 4);
    size_t o_bcur    = off; off += align256((size_t)NB * 4);
    size_t needed = off;

    char* wsb = (char*)d_ws;
    float* cur0 = (float*)(wsb + o_cur);
    float* nxt0 = (float*)(wsb + o_nxt);

    if (ws_size >= needed) {
        // ================= bucketed CSR path =================
        int2* colval = (int2*)(wsb + o_colval);
        int*  rowPtr = (int*) (wsb + o_rowptr);
        int*  gcnt   = (int*) (wsb + o_gcnt);
        int*  bstart = (int*) (wsb + o_bstart);
        int*  bcur   = (int*) (wsb + o_bcur);
        int2* temp   = (int2*)nxt0;          // 76.8 MB, reused as 'nxt' later

        copy_concat_kernel<<<GRID_MEM, BLK, 0, stream>>>(uEmb, iEmb, cur0, acc,
                                                         n4u, n4total);

        hipMemsetAsync(gcnt, 0, (size_t)NB * 4, stream);
        bucket_hist_kernel<<<GRID_MEM, BLK, 0, stream>>>(row, gcnt);
        scan_buckets_kernel<<<1, 1024, 0, stream>>>(gcnt, bstart, bcur, rowPtr);
        partition_kernel<<<GRID_MEM, BLK, 0, stream>>>(row, col, val, bcur, temp);
        bucket_sort_kernel<<<NB, 256, 0, stream>>>(bstart, temp, colval, rowPtr);

        // 3 layers, atomic-free
        const int GRID_SPMM = (N_NODES * 16 + BLK - 1) / BLK;   // 18750
        float* cur = cur0;
        float* nxt = nxt0;
        for (int l = 0; l < N_LAYERS; ++l) {
            int storeY = (l != N_LAYERS - 1);
            spmm_csr_kernel<<<GRID_SPMM, BLK, 0, stream>>>(rowPtr, colval, cur,
                                                           nxt, acc, storeY);
            float* t = cur; cur = nxt; nxt = t;
        }
    } else {
        // ================= fallback: atomic path =================
        copy_concat_kernel<<<GRID_MEM, BLK, 0, stream>>>(uEmb, iEmb, cur0, acc,
                                                         n4u, n4total);
        float* cur = cur0;
        float* nxt = nxt0;
        for (int l = 0; l < N_LAYERS; ++l) {
            hipMemsetAsync(nxt, 0, embBytes, stream);
            spmm_atomic_kernel<<<4096, BLK, 0, stream>>>(row, col, val, cur, nxt);
            acc_add_kernel<<<GRID_MEM, BLK, 0, stream>>>(acc, nxt, n4total);
            float* t = cur; cur = nxt; nxt = t;
        }
    }
}